// Round 8
// baseline (180.178 us; speedup 1.0000x reference)
//
#include <hip/hip_runtime.h>
#include <hip/hip_bf16.h>
#include <stdint.h>

#define M_DIM 8192
#define N_DIM 1024
#define K_DIM 4096

typedef __bf16 bf16x8 __attribute__((ext_vector_type(8)));
typedef float f32x4 __attribute__((ext_vector_type(4)));
typedef __hip_bfloat16 bf16_t;

__device__ __forceinline__ void gload_lds16(const void* g, void* l) {
  __builtin_amdgcn_global_load_lds(
      (const __attribute__((address_space(1))) void*)g,
      (__attribute__((address_space(3))) void*)l, 16, 0, 0);
}

// ---- pack W only: fp32 [1024][4096] -> bf16 tiled [rt][kt][256 rows][8 chunks]
// with st-swizzle pre-applied (chunk' = chunk ^ (row&7)).
__global__ __launch_bounds__(256) void pack_w(const float* __restrict__ W,
                                              int4* __restrict__ pB) {
  const unsigned t = blockIdx.x * 256 + threadIdx.x;   // < 524288
  const unsigned cp = t & 7;
  const unsigned tmp = t >> 3;
  const unsigned r = tmp & 255;
  const unsigned tmp2 = tmp >> 8;
  const unsigned kt = tmp2 & 63;
  const unsigned rt = tmp2 >> 6;
  const unsigned srow = (rt << 8) + r;
  const unsigned k0 = (kt << 6) + ((cp ^ (r & 7)) << 3);
  const float4* s = (const float4*)(W + (size_t)srow * 4096 + k0);
  float4 a = s[0], b = s[1];
  union { bf16_t h[8]; int4 v; } u;
  u.h[0] = __float2bfloat16(a.x); u.h[1] = __float2bfloat16(a.y);
  u.h[2] = __float2bfloat16(a.z); u.h[3] = __float2bfloat16(a.w);
  u.h[4] = __float2bfloat16(b.x); u.h[5] = __float2bfloat16(b.y);
  u.h[6] = __float2bfloat16(b.z); u.h[7] = __float2bfloat16(b.w);
  pB[t] = u.v;
}

// ---- 8-phase 256x256 GEMM, r7 pipelined snake + reg-staged A (no pack-A) ----
// 512 thr = 8 waves (2M x 4N), per-wave C = 128x64. B staged via
// global_load_lds from packed bf16; A staged global fp32 -> regs -> cvt ->
// swizzled ds_write (r6 path) with ONE shared 16-VGPR buffer gab:
//   gab role gb: issued P2(g-1) tail (Ah1(g+1) src) -> cvt_write P0(g) tail
//   gab role ga: issued P0(g) tail (Ah0(g+2) src)  -> cvt_write P2(g) tail
// ds_read schedule (1 phase ahead): P0: b1(g); P1: aO(g); P2: none;
// P3: aE(g+1) head + b0(g+1) tail.  [aE moved P2->P3 to cut reg pressure]
// FIFO vmcnt ledger (per thread; ops: P0 head Bh0x2, P0 tail gab4,
// P2 head Bh1x2, P2 tail gab4; entry invariant [gab4]):
//   P0 tail vmcnt(2): retires gab(gb role)        -> cvt_write Ah1(g+1)
//   P2 tail vmcnt(2): retires Bh0(g+1)+gab(ga)    -> cvt_write Ah0(g+2)
//   P3 end  vmcnt(4): retires Bh1(g+1)            -> b1 readable at P0(g+1)
// Every cvt_write has lgkm-drain -> barrier before first reader.
__device__ __forceinline__ void stage_half(const char* g, char* smem, int ldsoff, int tid) {
  gload_lds16(g + tid * 16, smem + ldsoff + tid * 16);
  gload_lds16(g + 8192 + tid * 16, smem + ldsoff + 8192 + tid * 16);
}

__device__ __forceinline__ void issue4(const float* g, float4* r) {
  r[0] = *(const float4*)(g);
  r[1] = *(const float4*)(g + (size_t)32 * K_DIM);
  r[2] = *(const float4*)(g + (size_t)64 * K_DIM);
  r[3] = *(const float4*)(g + (size_t)96 * K_DIM);
}

__device__ __forceinline__ void cvt_write(const float4* r, char* base, int o0) {
  #pragma unroll
  for (int i = 0; i < 4; ++i) {
    union { bf16_t h[4]; int2 v; } u;
    u.h[0] = __float2bfloat16(r[i].x); u.h[1] = __float2bfloat16(r[i].y);
    u.h[2] = __float2bfloat16(r[i].z); u.h[3] = __float2bfloat16(r[i].w);
    *(int2*)(base + o0 + i * 4096) = u.v;
  }
}

__global__ __launch_bounds__(512, 2) void gemm8(
    const float* __restrict__ Araw, const char* __restrict__ pB,
    float* __restrict__ V0, float* __restrict__ V1p, int NT) {
  extern __shared__ char smem[];
  const int tid = threadIdx.x;
  const int lane = tid & 63, wave = tid >> 6;
  const int wm = wave >> 2, wn = wave & 3;
  const int lrow = lane & 15, lkc = lane >> 4;

  const int cpx = (int)gridDim.x >> 3;
  const int swz = ((int)blockIdx.x & 7) * cpx + ((int)blockIdx.x >> 3);
  const int split = swz >> 7;
  const int rem = swz & 127;
  const int mt = rem >> 2, nt = rem & 3;

  const char* Bbase = pB + ((size_t)nt * 64 + (size_t)split * NT) * 32768;
  float* V = split ? V1p : V0;

  // Coalesced A source (r6): thread -> row (tid>>4)+i*32, 16B chunk (tid&15).
  const float* aG = Araw + (size_t)(mt * 256 + (tid >> 4)) * K_DIM +
                    (size_t)split * (NT * 64) + (tid & 15) * 4;
  const int wrO0 = (tid >> 4) * 128 + (((((tid & 15) >> 1)) ^ ((tid >> 4) & 7)) << 4) +
                   ((tid & 15) & 1) * 8;

  int colw[2];
  colw[0] = ((lkc) ^ (lrow & 7)) << 4;
  colw[1] = ((4 + lkc) ^ (lrow & 7)) << 4;
  int aRow[4], bRow[2];
  #pragma unroll
  for (int f = 0; f < 4; ++f) aRow[f] = (wm * 64 + f * 16 + lrow) * 128;
  #pragma unroll
  for (int f2 = 0; f2 < 2; ++f2) bRow[f2] = 32768 + (wn * 32 + f2 * 16 + lrow) * 128;

  f32x4 acc[2][4][2][2];
  #pragma unroll
  for (int a0 = 0; a0 < 2; ++a0)
    #pragma unroll
    for (int a1 = 0; a1 < 4; ++a1)
      #pragma unroll
      for (int a2 = 0; a2 < 2; ++a2)
        #pragma unroll
        for (int a3 = 0; a3 < 2; ++a3)
          acc[a0][a1][a2][a3] = (f32x4){0.f, 0.f, 0.f, 0.f};

  const int ktm = NT - 1;
  float4 gab[4], gt[4];

  // ---- Prologue: LDS gets Ah0(0),Ah1(0),Bh0(0),Bh1(0),Ah0(1); end with
  // outstanding [gab4 = Ah1(1) src] (= loop entry invariant).
  issue4(aG, gab);                                         // Ah0(0) src [4]
  issue4(aG + (size_t)128 * K_DIM, gt);                    // Ah1(0) src [8]
  stage_half(Bbase, smem, 32768, tid);                     // Bh0(0) [10]
  stage_half(Bbase + 16384, smem, 49152, tid);             // Bh1(0) [12]
  asm volatile("s_waitcnt vmcnt(8)" ::: "memory");
  cvt_write(gab, smem + 0, wrO0);                          // Ah0(0)
  asm volatile("s_waitcnt vmcnt(4)" ::: "memory");
  cvt_write(gt, smem + 16384, wrO0);                       // Ah1(0)
  issue4(aG + 64, gab);                                    // Ah0(1) src [8]
  asm volatile("s_waitcnt vmcnt(4)" ::: "memory");         // retire Bh0,Bh1
  asm volatile("s_waitcnt vmcnt(0)" ::: "memory");         // retire gab
  cvt_write(gab, smem + 65536, wrO0);                      // Ah0(1)
  issue4(aG + 64 + (size_t)128 * K_DIM, gab);              // Ah1(1) src [4] ✓
  asm volatile("s_waitcnt lgkmcnt(0)" ::: "memory");
  __builtin_amdgcn_s_barrier();

  bf16x8 aE[4][2], aO[4][2], b0[2][2], b1[2][2];
  #pragma unroll
  for (int f = 0; f < 4; ++f)
    #pragma unroll
    for (int s = 0; s < 2; ++s)
      aE[f][s] = *(const bf16x8*)(smem + aRow[f] + colw[s]);
  #pragma unroll
  for (int f2 = 0; f2 < 2; ++f2)
    #pragma unroll
    for (int s = 0; s < 2; ++s)
      b0[f2][s] = *(const bf16x8*)(smem + bRow[f2] + colw[s]);

  for (int g = 0; g < NT; ++g) {
    const int bb = g & 1, nbf = bb ^ 1;
    char* ab = smem + bb * 65536;
    char* nb = smem + nbf * 65536;
    const char* B1t = Bbase + (size_t)((g + 1) & ktm) * 32768;
    const size_t ka2 = (size_t)((g + 2) & ktm) * 64;

    // ---- P0: read b1(g); stage Bh0(g+1); MFMA M0N0;
    //      tail: vmcnt(2) -> cvt_write(gab->Ah1(g+1)); issue gab<-Ah0(g+2) ----
    #pragma unroll
    for (int f2 = 0; f2 < 2; ++f2)
      #pragma unroll
      for (int s = 0; s < 2; ++s)
        b1[f2][s] = *(const bf16x8*)(ab + bRow[f2] + 16384 + colw[s]);
    stage_half(B1t, smem, nbf * 65536 + 32768, tid);          // Bh0(g+1)
    __builtin_amdgcn_s_setprio(1);
    #pragma unroll
    for (int f = 0; f < 4; ++f)
      #pragma unroll
      for (int f2 = 0; f2 < 2; ++f2)
        #pragma unroll
        for (int s = 0; s < 2; ++s)
          acc[0][f][0][f2] = __builtin_amdgcn_mfma_f32_16x16x32_bf16(
              aE[f][s], b0[f2][s], acc[0][f][0][f2], 0, 0, 0);
    __builtin_amdgcn_s_setprio(0);
    asm volatile("s_waitcnt vmcnt(2)" ::: "memory");
    cvt_write(gab, nb + 16384, wrO0);                         // Ah1(g+1)
    issue4(aG + ka2, gab);                                    // Ah0(g+2) src
    asm volatile("s_waitcnt lgkmcnt(0)" ::: "memory");
    __builtin_amdgcn_sched_barrier(0);
    __builtin_amdgcn_s_barrier();

    // ---- P1: read aO(g); MFMA M0N1; barrier (no vm wait) -------------------
    #pragma unroll
    for (int f = 0; f < 4; ++f)
      #pragma unroll
      for (int s = 0; s < 2; ++s)
        aO[f][s] = *(const bf16x8*)(ab + aRow[f] + 16384 + colw[s]);
    __builtin_amdgcn_s_setprio(1);
    #pragma unroll
    for (int f = 0; f < 4; ++f)
      #pragma unroll
      for (int f2 = 0; f2 < 2; ++f2)
        #pragma unroll
        for (int s = 0; s < 2; ++s)
          acc[0][f][1][f2] = __builtin_amdgcn_mfma_f32_16x16x32_bf16(
              aE[f][s], b1[f2][s], acc[0][f][1][f2], 0, 0, 0);
    __builtin_amdgcn_s_setprio(0);
    __builtin_amdgcn_sched_barrier(0);
    __builtin_amdgcn_s_barrier();

    // ---- P2: stage Bh1(g+1); MFMA M1N1;
    //      tail: vmcnt(2) -> cvt_write(gab->Ah0(g+2)); issue gab<-Ah1(g+2) ----
    stage_half(B1t + 16384, smem, nbf * 65536 + 49152, tid);  // Bh1(g+1)
    __builtin_amdgcn_s_setprio(1);
    #pragma unroll
    for (int f = 0; f < 4; ++f)
      #pragma unroll
      for (int f2 = 0; f2 < 2; ++f2)
        #pragma unroll
        for (int s = 0; s < 2; ++s)
          acc[1][f][1][f2] = __builtin_amdgcn_mfma_f32_16x16x32_bf16(
              aO[f][s], b1[f2][s], acc[1][f][1][f2], 0, 0, 0);
    __builtin_amdgcn_s_setprio(0);
    asm volatile("s_waitcnt vmcnt(2)" ::: "memory");
    cvt_write(gab, ab, wrO0);                                 // Ah0(g+2)
    issue4(aG + ka2 + (size_t)128 * K_DIM, gab);              // Ah1(g+2) src
    asm volatile("s_waitcnt lgkmcnt(0)" ::: "memory");
    __builtin_amdgcn_sched_barrier(0);
    __builtin_amdgcn_s_barrier();

    // ---- P3: read aE(g+1); MFMA M1N0; tail: read b0(g+1); vmcnt(4) ---------
    #pragma unroll
    for (int f = 0; f < 4; ++f)
      #pragma unroll
      for (int s = 0; s < 2; ++s)
        aE[f][s] = *(const bf16x8*)(nb + aRow[f] + colw[s]);
    __builtin_amdgcn_s_setprio(1);
    #pragma unroll
    for (int f = 0; f < 4; ++f)
      #pragma unroll
      for (int f2 = 0; f2 < 2; ++f2)
        #pragma unroll
        for (int s = 0; s < 2; ++s)
          acc[1][f][0][f2] = __builtin_amdgcn_mfma_f32_16x16x32_bf16(
              aO[f][s], b0[f2][s], acc[1][f][0][f2], 0, 0, 0);
    __builtin_amdgcn_s_setprio(0);
    __builtin_amdgcn_sched_barrier(0);
    #pragma unroll
    for (int f2 = 0; f2 < 2; ++f2)
      #pragma unroll
      for (int s = 0; s < 2; ++s)
        b0[f2][s] = *(const bf16x8*)(nb + bRow[f2] + colw[s]);
    asm volatile("s_waitcnt vmcnt(4)" ::: "memory");
    __builtin_amdgcn_sched_barrier(0);
    __builtin_amdgcn_s_barrier();
  }

  // C-write: frag layout col=lane&15, row=(lane>>4)*4+reg (m89-verified).
  const int lq = lane >> 4;
  #pragma unroll
  for (int qm = 0; qm < 2; ++qm)
    #pragma unroll
    for (int f = 0; f < 4; ++f) {
      const int rowg = mt * 256 + qm * 128 + wm * 64 + f * 16 + lq * 4;
      #pragma unroll
      for (int reg = 0; reg < 4; ++reg) {
        float* Vr = V + (size_t)(rowg + reg) * N_DIM + nt * 256 + wn * 32 + lrow;
        #pragma unroll
        for (int qn = 0; qn < 2; ++qn)
          #pragma unroll
          for (int f2 = 0; f2 < 2; ++f2)
            Vr[qn * 128 + f2 * 16] = acc[qm][f][qn][f2][reg];
      }
    }
}

// ---- Householder epilogue: combines split-K partials, in-place on d_out ------
__global__ __launch_bounds__(256) void householder_ep(
    const float* __restrict__ x, const float* __restrict__ bias,
    float* __restrict__ vio, const float* __restrict__ V2,
    float* __restrict__ logdet) {
  const int row = blockIdx.x;
  const int t = threadIdx.x;
  float4* vr = (float4*)(vio + (size_t)row * N_DIM);
  const float4* xr = (const float4*)(x + (size_t)row * N_DIM);
  const float4* br = (const float4*)bias;

  float4 v = vr[t];
  if (V2) {
    float4 v2 = ((const float4*)(V2 + (size_t)row * N_DIM))[t];
    v.x += v2.x; v.y += v2.y; v.z += v2.z; v.w += v2.w;
  }
  float4 bb = br[t];
  v.x += bb.x; v.y += bb.y; v.z += bb.z; v.w += bb.w;
  float4 xx = xr[t];

  float dot = v.x * xx.x + v.y * xx.y + v.z * xx.z + v.w * xx.w;
  float nsq = v.x * v.x + v.y * v.y + v.z * v.z + v.w * v.w;

  #pragma unroll
  for (int off = 32; off > 0; off >>= 1) {
    dot += __shfl_down(dot, off);
    nsq += __shfl_down(nsq, off);
  }
  __shared__ float sd[4], sn[4];
  if ((t & 63) == 0) { sd[t >> 6] = dot; sn[t >> 6] = nsq; }
  __syncthreads();
  dot = sd[0] + sd[1] + sd[2] + sd[3];
  nsq = sn[0] + sn[1] + sn[2] + sn[3];

  const float f = 2.0f * dot / sqrtf(nsq);
  float4 o;
  o.x = xx.x - f * v.x;
  o.y = xx.y - f * v.y;
  o.z = xx.z - f * v.z;
  o.w = xx.w - f * v.w;
  vr[t] = o;
  if (t == 0) logdet[row] = 0.0f;
}

extern "C" void kernel_launch(void* const* d_in, const int* in_sizes, int n_in,
                              void* d_out, int out_size, void* d_ws, size_t ws_size,
                              hipStream_t stream) {
  const float* x   = (const float*)d_in[0];   // [8192,1024]
  const float* enc = (const float*)d_in[1];   // [8192,4096]
  const float* W   = (const float*)d_in[2];   // [1024,4096]
  const float* b   = (const float*)d_in[3];   // [1024]

  float* out    = (float*)d_out;
  float* v      = out;                              // V partial 0 lives in d_out
  float* logdet = out + (size_t)M_DIM * N_DIM;

  char*  packB = (char*)d_ws;                               // 8 MB
  float* V2    = (float*)(packB + (size_t)8 * 1024 * 1024); // 32 MB

  const size_t need2 = (size_t)40 * 1024 * 1024;
  const int nsplit = (ws_size >= need2) ? 2 : 1;

  pack_w<<<2048, 256, 0, stream>>>(W, (int4*)packB);

  hipFuncSetAttribute((const void*)gemm8, hipFuncAttributeMaxDynamicSharedMemorySize, 131072);
  gemm8<<<dim3(128 * nsplit), 512, 131072, stream>>>(
      enc, packB, v, nsplit == 2 ? V2 : nullptr, 64 / nsplit);

  householder_ep<<<M_DIM, 256, 0, stream>>>(x, b, v, nsplit == 2 ? V2 : nullptr, logdet);
}

// Round 9
// 118.798 us; speedup vs baseline: 1.5167x; 1.5167x over previous
//
#include <hip/hip_runtime.h>
#include <hip/hip_bf16.h>
#include <stdint.h>

#define M_DIM 8192
#define N_DIM 1024
#define K_DIM 4096

typedef __bf16 bf16x8 __attribute__((ext_vector_type(8)));
typedef float f32x4 __attribute__((ext_vector_type(4)));
typedef __hip_bfloat16 bf16_t;

__device__ __forceinline__ void gload_lds16(const void* g, void* l) {
  __builtin_amdgcn_global_load_lds(
      (const __attribute__((address_space(1))) void*)g,
      (__attribute__((address_space(3))) void*)l, 16, 0, 0);
}

// ---- pack: fp32 [R][4096] -> bf16 tiled [rt][kt][256 rows][8 chunks], with
// st-swizzle pre-applied (chunk' = chunk ^ (row&7)); enc+W in one launch.
__global__ __launch_bounds__(256) void pack_both(const float* __restrict__ enc,
                                                 const float* __restrict__ W,
                                                 int4* __restrict__ pA,
                                                 int4* __restrict__ pB) {
  const unsigned gtid = blockIdx.x * 256 + threadIdx.x;
  const float* src;
  int4* dst;
  unsigned t;
  if (gtid < 4194304u) { src = enc; dst = pA; t = gtid; }          // 8192*4096/8
  else                 { src = W;   dst = pB; t = gtid - 4194304u; }
  const unsigned cp = t & 7;
  const unsigned tmp = t >> 3;
  const unsigned r = tmp & 255;
  const unsigned tmp2 = tmp >> 8;
  const unsigned kt = tmp2 & 63;
  const unsigned rt = tmp2 >> 6;
  const unsigned srow = (rt << 8) + r;
  const unsigned k0 = (kt << 6) + ((cp ^ (r & 7)) << 3);
  const float4* s = (const float4*)(src + (size_t)srow * 4096 + k0);
  float4 a = s[0], b = s[1];
  union { bf16_t h[8]; int4 v; } u;
  u.h[0] = __float2bfloat16(a.x); u.h[1] = __float2bfloat16(a.y);
  u.h[2] = __float2bfloat16(a.z); u.h[3] = __float2bfloat16(a.w);
  u.h[4] = __float2bfloat16(b.x); u.h[5] = __float2bfloat16(b.y);
  u.h[6] = __float2bfloat16(b.z); u.h[7] = __float2bfloat16(b.w);
  dst[t] = u.v;
}

// ---- 8-phase 256x256 GEMM, pipelined reads + ALL-PRE-SATISFIED vmcnt (r9) ---
// 512 thr = 8 waves (2M x 4N), per-wave C = 128x64, snake M0N0->M0N1->M1N1->
// M1N0. All staging global_load_lds from pre-swizzled packed bf16.
// r9 change vs r7: stages re-spread so every vmcnt has >=3 phases of flight
// (r7 had two 1.5-phase waits < HBM latency; in 1-block/CU lockstep every
// wave pays those stalls).
// Per tile g:  P0: read b1(g); stage Bh0(g+1),Bh1(g+1); MFMA M0N0; vmcnt(6)
//              P1: read aO(g); stage Ah1(g+1);          MFMA M0N1; no wait
//              P2:              stage Ah0(g+2);          MFMA M1N1; vmcnt(8)
//              P3: read aE(g+1);                         MFMA M1N0;
//                  vmcnt(4); read b0(g+1)
// FIFO ledger (entry invariant [Ah1(g)2, Ah0(g+1)2]):
//   P0-end vmcnt(6): retires Ah1(g)     (staged P1(g-1), 3-ph flight)
//   P2-end vmcnt(8): retires Ah0(g+1)   (staged P2(g-1), 4-ph flight)
//   P3     vmcnt(4): retires B(g+1)x4   (staged P0(g),   3-ph flight)
// Slot overwrite gaps all >=3 phases (Bh0: last read P3(g-2) vs stage P0(g);
// Bh1: P0(g-1) vs P0(g); Ah1: P1(g-1) vs P1(g); Ah0: P3(g-1) vs P2(g)).
__device__ __forceinline__ void stage_half(const char* g, char* smem, int ldsoff, int tid) {
  gload_lds16(g + tid * 16, smem + ldsoff + tid * 16);
  gload_lds16(g + 8192 + tid * 16, smem + ldsoff + 8192 + tid * 16);
}

__global__ __launch_bounds__(512, 2) void gemm8(
    const char* __restrict__ pA, const char* __restrict__ pB,
    float* __restrict__ V0, float* __restrict__ V1p, int NT) {
  extern __shared__ char smem[];
  const int tid = threadIdx.x;
  const int lane = tid & 63, wave = tid >> 6;
  const int wm = wave >> 2, wn = wave & 3;
  const int lrow = lane & 15, lkc = lane >> 4;

  // XCD-aware swizzle (grid 128/256 -> %8==0, bijective)
  const int cpx = (int)gridDim.x >> 3;
  const int swz = ((int)blockIdx.x & 7) * cpx + ((int)blockIdx.x >> 3);
  const int split = swz >> 7;
  const int rem = swz & 127;
  const int mt = rem >> 2, nt = rem & 3;

  const char* Abase = pA + ((size_t)mt * 64 + (size_t)split * NT) * 32768;
  const char* Bbase = pB + ((size_t)nt * 64 + (size_t)split * NT) * 32768;
  float* V = split ? V1p : V0;

  // Swizzle folds to per-lane constants ((row&7)==(lrow&7) for all frag rows).
  int colw[2];
  colw[0] = ((lkc) ^ (lrow & 7)) << 4;
  colw[1] = ((4 + lkc) ^ (lrow & 7)) << 4;
  int aRow[4], bRow[2];
  #pragma unroll
  for (int f = 0; f < 4; ++f) aRow[f] = (wm * 64 + f * 16 + lrow) * 128;
  #pragma unroll
  for (int f2 = 0; f2 < 2; ++f2) bRow[f2] = 32768 + (wn * 32 + f2 * 16 + lrow) * 128;

  f32x4 acc[2][4][2][2];
  #pragma unroll
  for (int a0 = 0; a0 < 2; ++a0)
    #pragma unroll
    for (int a1 = 0; a1 < 4; ++a1)
      #pragma unroll
      for (int a2 = 0; a2 < 2; ++a2)
        #pragma unroll
        for (int a3 = 0; a3 < 2; ++a3)
          acc[a0][a1][a2][a3] = (f32x4){0.f, 0.f, 0.f, 0.f};

  const int ktm = NT - 1;

  // ---- Prologue: stage tile-0 (Ah0,Bh0,Bh1 first, then Ah1) + Ah0(1);
  // vmcnt(4) retires the first three -> entry invariant [Ah1(0)2, Ah0(1)2].
  stage_half(Abase,         smem, 0, tid);       // Ah0(0)
  stage_half(Bbase,         smem, 32768, tid);   // Bh0(0)
  stage_half(Bbase + 16384, smem, 49152, tid);   // Bh1(0)
  stage_half(Abase + 16384, smem, 16384, tid);   // Ah1(0)
  stage_half(Abase + 32768, smem, 65536, tid);   // Ah0(1)
  asm volatile("s_waitcnt vmcnt(4)" ::: "memory");
  __builtin_amdgcn_sched_barrier(0);
  __builtin_amdgcn_s_barrier();

  bf16x8 aE[4][2], aO[4][2], b0[2][2], b1[2][2];
  #pragma unroll
  for (int f = 0; f < 4; ++f)
    #pragma unroll
    for (int s = 0; s < 2; ++s)
      aE[f][s] = *(const bf16x8*)(smem + aRow[f] + colw[s]);
  #pragma unroll
  for (int f2 = 0; f2 < 2; ++f2)
    #pragma unroll
    for (int s = 0; s < 2; ++s)
      b0[f2][s] = *(const bf16x8*)(smem + bRow[f2] + colw[s]);

  for (int g = 0; g < NT; ++g) {
    const int bb = g & 1, nbf = bb ^ 1;
    char* ab = smem + bb * 65536;
    char* nb = smem + nbf * 65536;
    const char* A1t = Abase + (size_t)((g + 1) & ktm) * 32768;
    const char* B1t = Bbase + (size_t)((g + 1) & ktm) * 32768;
    const char* A2t = Abase + (size_t)((g + 2) & ktm) * 32768;

    // ---- P0: read b1(g); stage Bh0(g+1)+Bh1(g+1); MFMA M0N0; vmcnt(6) ------
    #pragma unroll
    for (int f2 = 0; f2 < 2; ++f2)
      #pragma unroll
      for (int s = 0; s < 2; ++s)
        b1[f2][s] = *(const bf16x8*)(ab + bRow[f2] + 16384 + colw[s]);
    stage_half(B1t, smem, nbf * 65536 + 32768, tid);          // Bh0(g+1)
    stage_half(B1t + 16384, smem, nbf * 65536 + 49152, tid);  // Bh1(g+1)
    __builtin_amdgcn_s_setprio(1);
    #pragma unroll
    for (int f = 0; f < 4; ++f)
      #pragma unroll
      for (int f2 = 0; f2 < 2; ++f2)
        #pragma unroll
        for (int s = 0; s < 2; ++s)
          acc[0][f][0][f2] = __builtin_amdgcn_mfma_f32_16x16x32_bf16(
              aE[f][s], b0[f2][s], acc[0][f][0][f2], 0, 0, 0);
    __builtin_amdgcn_s_setprio(0);
    asm volatile("s_waitcnt vmcnt(6)" ::: "memory");
    __builtin_amdgcn_sched_barrier(0);
    __builtin_amdgcn_s_barrier();

    // ---- P1: read aO(g); stage Ah1(g+1); MFMA M0N1; no wait ----------------
    #pragma unroll
    for (int f = 0; f < 4; ++f)
      #pragma unroll
      for (int s = 0; s < 2; ++s)
        aO[f][s] = *(const bf16x8*)(ab + aRow[f] + 16384 + colw[s]);
    stage_half(A1t + 16384, smem, nbf * 65536 + 16384, tid);  // Ah1(g+1)
    __builtin_amdgcn_s_setprio(1);
    #pragma unroll
    for (int f = 0; f < 4; ++f)
      #pragma unroll
      for (int f2 = 0; f2 < 2; ++f2)
        #pragma unroll
        for (int s = 0; s < 2; ++s)
          acc[0][f][1][f2] = __builtin_amdgcn_mfma_f32_16x16x32_bf16(
              aE[f][s], b1[f2][s], acc[0][f][1][f2], 0, 0, 0);
    __builtin_amdgcn_s_setprio(0);
    __builtin_amdgcn_sched_barrier(0);
    __builtin_amdgcn_s_barrier();

    // ---- P2: stage Ah0(g+2); MFMA M1N1; vmcnt(8) ---------------------------
    stage_half(A2t, smem, bb * 65536, tid);                   // Ah0(g+2)
    __builtin_amdgcn_s_setprio(1);
    #pragma unroll
    for (int f = 0; f < 4; ++f)
      #pragma unroll
      for (int f2 = 0; f2 < 2; ++f2)
        #pragma unroll
        for (int s = 0; s < 2; ++s)
          acc[1][f][1][f2] = __builtin_amdgcn_mfma_f32_16x16x32_bf16(
              aO[f][s], b1[f2][s], acc[1][f][1][f2], 0, 0, 0);
    __builtin_amdgcn_s_setprio(0);
    asm volatile("s_waitcnt vmcnt(8)" ::: "memory");
    __builtin_amdgcn_sched_barrier(0);
    __builtin_amdgcn_s_barrier();

    // ---- P3: read aE(g+1); MFMA M1N0; vmcnt(4); read b0(g+1) ---------------
    #pragma unroll
    for (int f = 0; f < 4; ++f)
      #pragma unroll
      for (int s = 0; s < 2; ++s)
        aE[f][s] = *(const bf16x8*)(nb + aRow[f] + colw[s]);
    __builtin_amdgcn_s_setprio(1);
    #pragma unroll
    for (int f = 0; f < 4; ++f)
      #pragma unroll
      for (int f2 = 0; f2 < 2; ++f2)
        #pragma unroll
        for (int s = 0; s < 2; ++s)
          acc[1][f][0][f2] = __builtin_amdgcn_mfma_f32_16x16x32_bf16(
              aO[f][s], b0[f2][s], acc[1][f][0][f2], 0, 0, 0);
    __builtin_amdgcn_s_setprio(0);
    __builtin_amdgcn_sched_barrier(0);
    asm volatile("s_waitcnt vmcnt(4)" ::: "memory");
    #pragma unroll
    for (int f2 = 0; f2 < 2; ++f2)
      #pragma unroll
      for (int s = 0; s < 2; ++s)
        b0[f2][s] = *(const bf16x8*)(nb + bRow[f2] + colw[s]);
    __builtin_amdgcn_sched_barrier(0);
    __builtin_amdgcn_s_barrier();
  }

  // C-write: frag layout col=lane&15, row=(lane>>4)*4+reg (m89-verified).
  const int lq = lane >> 4;
  #pragma unroll
  for (int qm = 0; qm < 2; ++qm)
    #pragma unroll
    for (int f = 0; f < 4; ++f) {
      const int rowg = mt * 256 + qm * 128 + wm * 64 + f * 16 + lq * 4;
      #pragma unroll
      for (int reg = 0; reg < 4; ++reg) {
        float* Vr = V + (size_t)(rowg + reg) * N_DIM + nt * 256 + wn * 32 + lrow;
        #pragma unroll
        for (int qn = 0; qn < 2; ++qn)
          #pragma unroll
          for (int f2 = 0; f2 < 2; ++f2)
            Vr[qn * 128 + f2 * 16] = acc[qm][f][qn][f2][reg];
      }
    }
}

// ---- Householder epilogue: combines split-K partials, in-place on d_out ------
__global__ __launch_bounds__(256) void householder_ep(
    const float* __restrict__ x, const float* __restrict__ bias,
    float* __restrict__ vio, const float* __restrict__ V2,
    float* __restrict__ logdet) {
  const int row = blockIdx.x;
  const int t = threadIdx.x;
  float4* vr = (float4*)(vio + (size_t)row * N_DIM);
  const float4* xr = (const float4*)(x + (size_t)row * N_DIM);
  const float4* br = (const float4*)bias;

  float4 v = vr[t];
  if (V2) {
    float4 v2 = ((const float4*)(V2 + (size_t)row * N_DIM))[t];
    v.x += v2.x; v.y += v2.y; v.z += v2.z; v.w += v2.w;
  }
  float4 bb = br[t];
  v.x += bb.x; v.y += bb.y; v.z += bb.z; v.w += bb.w;
  float4 xx = xr[t];

  float dot = v.x * xx.x + v.y * xx.y + v.z * xx.z + v.w * xx.w;
  float nsq = v.x * v.x + v.y * v.y + v.z * v.z + v.w * v.w;

  #pragma unroll
  for (int off = 32; off > 0; off >>= 1) {
    dot += __shfl_down(dot, off);
    nsq += __shfl_down(nsq, off);
  }
  __shared__ float sd[4], sn[4];
  if ((t & 63) == 0) { sd[t >> 6] = dot; sn[t >> 6] = nsq; }
  __syncthreads();
  dot = sd[0] + sd[1] + sd[2] + sd[3];
  nsq = sn[0] + sn[1] + sn[2] + sn[3];

  const float f = 2.0f * dot / sqrtf(nsq);
  float4 o;
  o.x = xx.x - f * v.x;
  o.y = xx.y - f * v.y;
  o.z = xx.z - f * v.z;
  o.w = xx.w - f * v.w;
  vr[t] = o;
  if (t == 0) logdet[row] = 0.0f;
}

extern "C" void kernel_launch(void* const* d_in, const int* in_sizes, int n_in,
                              void* d_out, int out_size, void* d_ws, size_t ws_size,
                              hipStream_t stream) {
  const float* x   = (const float*)d_in[0];   // [8192,1024]
  const float* enc = (const float*)d_in[1];   // [8192,4096]
  const float* W   = (const float*)d_in[2];   // [1024,4096]
  const float* b   = (const float*)d_in[3];   // [1024]

  float* out    = (float*)d_out;
  float* v      = out;                              // V partial 0 lives in d_out
  float* logdet = out + (size_t)M_DIM * N_DIM;

  char*  packA = (char*)d_ws;                       // 64 MB
  char*  packB = packA + (size_t)64 * 1024 * 1024;  //  8 MB
  float* V2    = (float*)(packB + (size_t)8 * 1024 * 1024);  // 32 MB

  const size_t need2 = (size_t)104 * 1024 * 1024;
  const int nsplit = (ws_size >= need2) ? 2 : 1;

  pack_both<<<18432, 256, 0, stream>>>(enc, W, (int4*)packA, (int4*)packB);

  hipFuncSetAttribute((const void*)gemm8, hipFuncAttributeMaxDynamicSharedMemorySize, 131072);
  gemm8<<<dim3(128 * nsplit), 512, 131072, stream>>>(
      packA, packB, v, nsplit == 2 ? V2 : nullptr, 64 / nsplit);

  householder_ep<<<M_DIM, 256, 0, stream>>>(x, b, v, nsplit == 2 ? V2 : nullptr, logdet);
}

// Round 10
// 116.238 us; speedup vs baseline: 1.5501x; 1.0220x over previous
//
#include <hip/hip_runtime.h>
#include <hip/hip_bf16.h>
#include <stdint.h>

#define M_DIM 8192
#define N_DIM 1024
#define K_DIM 4096

typedef __bf16 bf16x8 __attribute__((ext_vector_type(8)));
typedef float f32x4 __attribute__((ext_vector_type(4)));
typedef __hip_bfloat16 bf16_t;

__device__ __forceinline__ void gload_lds16(const void* g, void* l) {
  __builtin_amdgcn_global_load_lds(
      (const __attribute__((address_space(1))) void*)g,
      (__attribute__((address_space(3))) void*)l, 16, 0, 0);
}

__device__ __forceinline__ float b2f(unsigned short u) {
  union { unsigned i; float f; } x;
  x.i = ((unsigned)u) << 16;
  return x.f;
}

// ---- pack: fp32 [R][4096] -> bf16 tiled [rt][kt][256 rows][8 chunks], with
// st-swizzle pre-applied (chunk' = chunk ^ (row&7)); enc+W in one launch.
__global__ __launch_bounds__(256) void pack_both(const float* __restrict__ enc,
                                                 const float* __restrict__ W,
                                                 int4* __restrict__ pA,
                                                 int4* __restrict__ pB) {
  const unsigned gtid = blockIdx.x * 256 + threadIdx.x;
  const float* src;
  int4* dst;
  unsigned t;
  if (gtid < 4194304u) { src = enc; dst = pA; t = gtid; }          // 8192*4096/8
  else                 { src = W;   dst = pB; t = gtid - 4194304u; }
  const unsigned cp = t & 7;
  const unsigned tmp = t >> 3;
  const unsigned r = tmp & 255;
  const unsigned tmp2 = tmp >> 8;
  const unsigned kt = tmp2 & 63;
  const unsigned rt = tmp2 >> 6;
  const unsigned srow = (rt << 8) + r;
  const unsigned k0 = (kt << 6) + ((cp ^ (r & 7)) << 3);
  const float4* s = (const float4*)(src + (size_t)srow * 4096 + k0);
  float4 a = s[0], b = s[1];
  union { bf16_t h[8]; int4 v; } u;
  u.h[0] = __float2bfloat16(a.x); u.h[1] = __float2bfloat16(a.y);
  u.h[2] = __float2bfloat16(a.z); u.h[3] = __float2bfloat16(a.w);
  u.h[4] = __float2bfloat16(b.x); u.h[5] = __float2bfloat16(b.y);
  u.h[6] = __float2bfloat16(b.z); u.h[7] = __float2bfloat16(b.w);
  dst[t] = u.v;
}

// ---- 8-phase 256x256 GEMM: r9 ledger + READS-AT-TAIL (r10) -------------------
// 512 thr = 8 waves (2M x 4N), per-wave C = 128x64, snake M0N0->M0N1->M1N1->
// M1N0. All staging global_load_lds from pre-swizzled packed bf16.
// r10 change vs r9: each phase's next-operand ds_reads moved AFTER the MFMA
// cluster (tail), so the LDS pipe services them during barrier convergence
// (m201's mechanism) instead of competing with the same phase's MFMA issue.
// Stage/vmcnt ledger identical to r9 (entry invariant [Ah1(g)2, Ah0(g+1)2]):
//   P0: stage Bh0/Bh1(g+1); MFMA(aE,b0); tail read b1(g);  vmcnt(6)
//   P1: stage Ah1(g+1);     MFMA(aE,b1); tail read aO(g);  no wait
//   P2: stage Ah0(g+2);     MFMA(aO,b1); vmcnt(8); tail read aE(g+1)
//   P3:                     MFMA(aO,b0); vmcnt(4); tail read b0(g+1)
// Slot-overwrite gaps all >=2 phases with a barrier between any read and the
// staging wave's issue (re-verified for tail positions).
__device__ __forceinline__ void stage_half(const char* g, char* smem, int ldsoff, int tid) {
  gload_lds16(g + tid * 16, smem + ldsoff + tid * 16);
  gload_lds16(g + 8192 + tid * 16, smem + ldsoff + 8192 + tid * 16);
}

__global__ __launch_bounds__(512, 2) void gemm8(
    const char* __restrict__ pA, const char* __restrict__ pB,
    bf16_t* __restrict__ V0, bf16_t* __restrict__ V1p, int NT) {
  extern __shared__ char smem[];
  const int tid = threadIdx.x;
  const int lane = tid & 63, wave = tid >> 6;
  const int wm = wave >> 2, wn = wave & 3;
  const int lrow = lane & 15, lkc = lane >> 4;

  // XCD-aware swizzle (grid 128/256 -> %8==0, bijective)
  const int cpx = (int)gridDim.x >> 3;
  const int swz = ((int)blockIdx.x & 7) * cpx + ((int)blockIdx.x >> 3);
  const int split = swz >> 7;
  const int rem = swz & 127;
  const int mt = rem >> 2, nt = rem & 3;

  const char* Abase = pA + ((size_t)mt * 64 + (size_t)split * NT) * 32768;
  const char* Bbase = pB + ((size_t)nt * 64 + (size_t)split * NT) * 32768;
  bf16_t* V = split ? V1p : V0;

  // Swizzle folds to per-lane constants ((row&7)==(lrow&7) for all frag rows).
  int colw[2];
  colw[0] = ((lkc) ^ (lrow & 7)) << 4;
  colw[1] = ((4 + lkc) ^ (lrow & 7)) << 4;
  int aRow[4], bRow[2];
  #pragma unroll
  for (int f = 0; f < 4; ++f) aRow[f] = (wm * 64 + f * 16 + lrow) * 128;
  #pragma unroll
  for (int f2 = 0; f2 < 2; ++f2) bRow[f2] = 32768 + (wn * 32 + f2 * 16 + lrow) * 128;

  f32x4 acc[2][4][2][2];
  #pragma unroll
  for (int a0 = 0; a0 < 2; ++a0)
    #pragma unroll
    for (int a1 = 0; a1 < 4; ++a1)
      #pragma unroll
      for (int a2 = 0; a2 < 2; ++a2)
        #pragma unroll
        for (int a3 = 0; a3 < 2; ++a3)
          acc[a0][a1][a2][a3] = (f32x4){0.f, 0.f, 0.f, 0.f};

  const int ktm = NT - 1;

  // ---- Prologue: stage tile-0 (Ah0,Bh0,Bh1 first, then Ah1) + Ah0(1);
  // vmcnt(4) retires the first three -> entry invariant [Ah1(0)2, Ah0(1)2].
  stage_half(Abase,         smem, 0, tid);       // Ah0(0)
  stage_half(Bbase,         smem, 32768, tid);   // Bh0(0)
  stage_half(Bbase + 16384, smem, 49152, tid);   // Bh1(0)
  stage_half(Abase + 16384, smem, 16384, tid);   // Ah1(0)
  stage_half(Abase + 32768, smem, 65536, tid);   // Ah0(1)
  asm volatile("s_waitcnt vmcnt(4)" ::: "memory");
  __builtin_amdgcn_sched_barrier(0);
  __builtin_amdgcn_s_barrier();

  bf16x8 aE[4][2], aO[4][2], b0[2][2], b1[2][2];
  #pragma unroll
  for (int f = 0; f < 4; ++f)
    #pragma unroll
    for (int s = 0; s < 2; ++s)
      aE[f][s] = *(const bf16x8*)(smem + aRow[f] + colw[s]);
  #pragma unroll
  for (int f2 = 0; f2 < 2; ++f2)
    #pragma unroll
    for (int s = 0; s < 2; ++s)
      b0[f2][s] = *(const bf16x8*)(smem + bRow[f2] + colw[s]);

  for (int g = 0; g < NT; ++g) {
    const int bb = g & 1, nbf = bb ^ 1;
    char* ab = smem + bb * 65536;
    char* nb = smem + nbf * 65536;
    const char* A1t = Abase + (size_t)((g + 1) & ktm) * 32768;
    const char* B1t = Bbase + (size_t)((g + 1) & ktm) * 32768;
    const char* A2t = Abase + (size_t)((g + 2) & ktm) * 32768;

    // ---- P0: stage Bh0/Bh1(g+1); MFMA M0N0; tail read b1(g); vmcnt(6) ------
    stage_half(B1t, smem, nbf * 65536 + 32768, tid);          // Bh0(g+1)
    stage_half(B1t + 16384, smem, nbf * 65536 + 49152, tid);  // Bh1(g+1)
    __builtin_amdgcn_s_setprio(1);
    #pragma unroll
    for (int f = 0; f < 4; ++f)
      #pragma unroll
      for (int f2 = 0; f2 < 2; ++f2)
        #pragma unroll
        for (int s = 0; s < 2; ++s)
          acc[0][f][0][f2] = __builtin_amdgcn_mfma_f32_16x16x32_bf16(
              aE[f][s], b0[f2][s], acc[0][f][0][f2], 0, 0, 0);
    __builtin_amdgcn_s_setprio(0);
    __builtin_amdgcn_sched_barrier(0);
    #pragma unroll
    for (int f2 = 0; f2 < 2; ++f2)
      #pragma unroll
      for (int s = 0; s < 2; ++s)
        b1[f2][s] = *(const bf16x8*)(ab + bRow[f2] + 16384 + colw[s]);
    asm volatile("s_waitcnt vmcnt(6)" ::: "memory");
    __builtin_amdgcn_sched_barrier(0);
    __builtin_amdgcn_s_barrier();

    // ---- P1: stage Ah1(g+1); MFMA M0N1; tail read aO(g) --------------------
    stage_half(A1t + 16384, smem, nbf * 65536 + 16384, tid);  // Ah1(g+1)
    __builtin_amdgcn_s_setprio(1);
    #pragma unroll
    for (int f = 0; f < 4; ++f)
      #pragma unroll
      for (int f2 = 0; f2 < 2; ++f2)
        #pragma unroll
        for (int s = 0; s < 2; ++s)
          acc[0][f][1][f2] = __builtin_amdgcn_mfma_f32_16x16x32_bf16(
              aE[f][s], b1[f2][s], acc[0][f][1][f2], 0, 0, 0);
    __builtin_amdgcn_s_setprio(0);
    __builtin_amdgcn_sched_barrier(0);
    #pragma unroll
    for (int f = 0; f < 4; ++f)
      #pragma unroll
      for (int s = 0; s < 2; ++s)
        aO[f][s] = *(const bf16x8*)(ab + aRow[f] + 16384 + colw[s]);
    __builtin_amdgcn_sched_barrier(0);
    __builtin_amdgcn_s_barrier();

    // ---- P2: stage Ah0(g+2); MFMA M1N1; vmcnt(8); tail read aE(g+1) --------
    stage_half(A2t, smem, bb * 65536, tid);                   // Ah0(g+2)
    __builtin_amdgcn_s_setprio(1);
    #pragma unroll
    for (int f = 0; f < 4; ++f)
      #pragma unroll
      for (int f2 = 0; f2 < 2; ++f2)
        #pragma unroll
        for (int s = 0; s < 2; ++s)
          acc[1][f][1][f2] = __builtin_amdgcn_mfma_f32_16x16x32_bf16(
              aO[f][s], b1[f2][s], acc[1][f][1][f2], 0, 0, 0);
    __builtin_amdgcn_s_setprio(0);
    __builtin_amdgcn_sched_barrier(0);
    asm volatile("s_waitcnt vmcnt(8)" ::: "memory");
    #pragma unroll
    for (int f = 0; f < 4; ++f)
      #pragma unroll
      for (int s = 0; s < 2; ++s)
        aE[f][s] = *(const bf16x8*)(nb + aRow[f] + colw[s]);
    __builtin_amdgcn_sched_barrier(0);
    __builtin_amdgcn_s_barrier();

    // ---- P3: MFMA M1N0; vmcnt(4); tail read b0(g+1) ------------------------
    __builtin_amdgcn_s_setprio(1);
    #pragma unroll
    for (int f = 0; f < 4; ++f)
      #pragma unroll
      for (int f2 = 0; f2 < 2; ++f2)
        #pragma unroll
        for (int s = 0; s < 2; ++s)
          acc[1][f][0][f2] = __builtin_amdgcn_mfma_f32_16x16x32_bf16(
              aO[f][s], b0[f2][s], acc[1][f][0][f2], 0, 0, 0);
    __builtin_amdgcn_s_setprio(0);
    __builtin_amdgcn_sched_barrier(0);
    asm volatile("s_waitcnt vmcnt(4)" ::: "memory");
    #pragma unroll
    for (int f2 = 0; f2 < 2; ++f2)
      #pragma unroll
      for (int s = 0; s < 2; ++s)
        b0[f2][s] = *(const bf16x8*)(nb + bRow[f2] + colw[s]);
    __builtin_amdgcn_sched_barrier(0);
    __builtin_amdgcn_s_barrier();
  }

  // C-write (bf16 partials): frag layout col=lane&15, row=(lane>>4)*4+reg.
  const int lq = lane >> 4;
  #pragma unroll
  for (int qm = 0; qm < 2; ++qm)
    #pragma unroll
    for (int f = 0; f < 4; ++f) {
      const int rowg = mt * 256 + qm * 128 + wm * 64 + f * 16 + lq * 4;
      #pragma unroll
      for (int reg = 0; reg < 4; ++reg) {
        bf16_t* Vr = V + (size_t)(rowg + reg) * N_DIM + nt * 256 + wn * 32 + lrow;
        #pragma unroll
        for (int qn = 0; qn < 2; ++qn)
          #pragma unroll
          for (int f2 = 0; f2 < 2; ++f2)
            Vr[qn * 128 + f2 * 16] = __float2bfloat16(acc[qm][f][qn][f2][reg]);
      }
    }
}

// ---- Householder epilogue: combine bf16 split-K partials, write f32 out ------
__global__ __launch_bounds__(256) void householder_ep(
    const float* __restrict__ x, const float* __restrict__ bias,
    const unsigned short* __restrict__ V0b, const unsigned short* __restrict__ V1b,
    float* __restrict__ out, float* __restrict__ logdet) {
  const int row = blockIdx.x;
  const int t = threadIdx.x;
  const float4* xr = (const float4*)(x + (size_t)row * N_DIM);
  const float4* br = (const float4*)bias;

  ushort4 u0 = ((const ushort4*)(V0b + (size_t)row * N_DIM))[t];
  float4 v;
  v.x = b2f(u0.x); v.y = b2f(u0.y); v.z = b2f(u0.z); v.w = b2f(u0.w);
  if (V1b) {
    ushort4 u1 = ((const ushort4*)(V1b + (size_t)row * N_DIM))[t];
    v.x += b2f(u1.x); v.y += b2f(u1.y); v.z += b2f(u1.z); v.w += b2f(u1.w);
  }
  float4 bb = br[t];
  v.x += bb.x; v.y += bb.y; v.z += bb.z; v.w += bb.w;
  float4 xx = xr[t];

  float dot = v.x * xx.x + v.y * xx.y + v.z * xx.z + v.w * xx.w;
  float nsq = v.x * v.x + v.y * v.y + v.z * v.z + v.w * v.w;

  #pragma unroll
  for (int off = 32; off > 0; off >>= 1) {
    dot += __shfl_down(dot, off);
    nsq += __shfl_down(nsq, off);
  }
  __shared__ float sd[4], sn[4];
  if ((t & 63) == 0) { sd[t >> 6] = dot; sn[t >> 6] = nsq; }
  __syncthreads();
  dot = sd[0] + sd[1] + sd[2] + sd[3];
  nsq = sn[0] + sn[1] + sn[2] + sn[3];

  const float f = 2.0f * dot / sqrtf(nsq);
  float4 o;
  o.x = xx.x - f * v.x;
  o.y = xx.y - f * v.y;
  o.z = xx.z - f * v.z;
  o.w = xx.w - f * v.w;
  ((float4*)(out + (size_t)row * N_DIM))[t] = o;
  if (t == 0) logdet[row] = 0.0f;
}

extern "C" void kernel_launch(void* const* d_in, const int* in_sizes, int n_in,
                              void* d_out, int out_size, void* d_ws, size_t ws_size,
                              hipStream_t stream) {
  const float* x   = (const float*)d_in[0];   // [8192,1024]
  const float* enc = (const float*)d_in[1];   // [8192,4096]
  const float* W   = (const float*)d_in[2];   // [1024,4096]
  const float* b   = (const float*)d_in[3];   // [1024]

  float* out    = (float*)d_out;
  float* logdet = out + (size_t)M_DIM * N_DIM;

  char*   packA = (char*)d_ws;                              // 64 MB
  char*   packB = packA + (size_t)64 * 1024 * 1024;         //  8 MB
  bf16_t* V0b   = (bf16_t*)(packB + (size_t)8 * 1024 * 1024);   // 16 MB
  bf16_t* V1b   = V0b + (size_t)M_DIM * N_DIM;                  // 16 MB

  const size_t need2 = (size_t)104 * 1024 * 1024;
  const int nsplit = (ws_size >= need2) ? 2 : 1;

  pack_both<<<18432, 256, 0, stream>>>(enc, W, (int4*)packA, (int4*)packB);

  hipFuncSetAttribute((const void*)gemm8, hipFuncAttributeMaxDynamicSharedMemorySize, 131072);
  gemm8<<<dim3(128 * nsplit), 512, 131072, stream>>>(
      packA, packB, V0b, nsplit == 2 ? V1b : nullptr, 64 / nsplit);

  householder_ep<<<M_DIM, 256, 0, stream>>>(
      x, b, (const unsigned short*)V0b,
      nsplit == 2 ? (const unsigned short*)V1b : nullptr, out, logdet);
}